// Round 11
// baseline (196.601 us; speedup 1.0000x reference)
//
#include <hip/hip_runtime.h>
#include <math.h>

#define LATENT   1024
#define WORD     64
#define NB_WORD  8192
#define BATCH    2048
#define NROWS    (BATCH * LATENT / WORD)   // 32768
#define NELEM    (BATCH * LATENT)          // 2097152

#define NCHUNK   8
#define CWCHUNK  (NB_WORD / NCHUNK)        // 1024
#define TPC      (CWCHUNK / 16)            // 64 tiles per chunk
#define NTILE    (NB_WORD / 16)            // 512 tiles
#define PKTS     (NTILE * 6 * 64)          // 196608 16B packets

typedef __attribute__((ext_vector_type(8))) __bf16 bf16x8;
typedef __attribute__((ext_vector_type(4))) float  f32x4;

// ------- kernel 1: fused e2 + epack (one emb read, r1 e2 chain order) -
// thread m owns codeword m: e2[m] = sum k&3-lane chains (bit-identical to
// r1); packets p=(tile*6+spl*2+Ks)*64 + q*16 + (m&15) hold 8 bf16 of split
// level spl for k = Ks*32 + q*8 + e.
__global__ __launch_bounds__(256) void vq_prep_kernel(
    const float* __restrict__ emb, float* __restrict__ e2,
    bf16x8* __restrict__ epack) {
    int m = blockIdx.x * 256 + threadIdx.x;
    int tile = m >> 4, l15 = m & 15;
    float s0 = 0.f, s1 = 0.f, s2 = 0.f, s3 = 0.f;
#pragma unroll
    for (int Ks = 0; Ks < 2; ++Ks) {
#pragma unroll
        for (int q = 0; q < 4; ++q) {
            const float4* s4 = reinterpret_cast<const float4*>(
                emb + (size_t)m * WORD + Ks * 32 + q * 8);
            float4 a = s4[0], b = s4[1];
            float tv[8] = {a.x, a.y, a.z, a.w, b.x, b.y, b.z, b.w};
            bf16x8 oh, om, ol;
#pragma unroll
            for (int e = 0; e < 8; ++e) {
                float v = tv[e];
                // e2 partial chains (same order as r1: s_{k&3}, k ascending)
                if ((e & 3) == 0) s0 = fmaf(v, v, s0);
                else if ((e & 3) == 1) s1 = fmaf(v, v, s1);
                else if ((e & 3) == 2) s2 = fmaf(v, v, s2);
                else s3 = fmaf(v, v, s3);
                __bf16 h  = (__bf16)v;
                float r1  = v - (float)h;
                __bf16 mm = (__bf16)r1;
                float r2  = r1 - (float)mm;
                __bf16 lo = (__bf16)r2;
                oh[e] = h; om[e] = mm; ol[e] = lo;
            }
            size_t base = ((size_t)tile * 6) * 64 + q * 16 + l15;
            epack[base + (size_t)(0 * 2 + Ks) * 64] = oh;
            epack[base + (size_t)(1 * 2 + Ks) * 64] = om;
            epack[base + (size_t)(2 * 2 + Ks) * 64] = ol;
        }
    }
    e2[m] = (s0 + s1) + (s2 + s3);
}

// ---------------- kernel 2: MFMA split-bf16 argmin --------------------
// Barrier-free, LDS-free. 256 thr = 4 INDEPENDENT waves; each wave owns
// 32 rows x the block's 1024-cw chunk (64 tiles). Per phase: 24 MFMA from
// register B-frags (6 x global b128, loaded one phase ahead into the same
// regs right after the MFMAs consume them), immediate fold. epack is
// pre-packed in per-lane fragment order, so lane l's loads ARE the frags
// (the former LDS staging was an identity permutation - removed).
__global__ __launch_bounds__(256)
__attribute__((amdgpu_waves_per_eu(4, 8)))
void vq_argmin_kernel(
    const float* __restrict__ z, const bf16x8* __restrict__ epack,
    const float* __restrict__ e2, unsigned long long* __restrict__ best) {

    const int tid   = threadIdx.x;
    const int lane  = tid & 63;
    const int wband = tid >> 6;               // 0..3
    const int l15   = lane & 15;
    const int l4    = lane >> 4;              // 0..3
    const int rowbase   = blockIdx.x * 128 + wband * 32;
    const int tile0     = blockIdx.y * TPC;
    const int chunkbase = blockIdx.y * CWCHUNK;
    const float* e2g    = e2 + chunkbase;
    const int off       = (blockIdx.x & 15) * 4;   // tile start offset (L2 spread)

    // ---- build A-frags (z 3-way bf16 split) in registers ----
    bf16x8 A[2][2][3];                         // [mt][Ks][spl]
    const float4* zf4 = reinterpret_cast<const float4*>(z);
#pragma unroll
    for (int mt = 0; mt < 2; ++mt) {
        int row = rowbase + mt * 16 + l15;
#pragma unroll
        for (int Ks = 0; Ks < 2; ++Ks) {
            float4 v0 = zf4[(size_t)row * 16 + Ks * 8 + l4 * 2];
            float4 v1 = zf4[(size_t)row * 16 + Ks * 8 + l4 * 2 + 1];
            float tv[8] = {v0.x, v0.y, v0.z, v0.w, v1.x, v1.y, v1.z, v1.w};
#pragma unroll
            for (int e = 0; e < 8; ++e) {
                float v = tv[e];
                __bf16 h  = (__bf16)v;
                float r1  = v - (float)h;
                __bf16 m  = (__bf16)r1;
                float r2  = r1 - (float)m;
                __bf16 lo = (__bf16)r2;
                A[mt][Ks][0][e] = h;
                A[mt][Ks][1][e] = m;
                A[mt][Ks][2][e] = lo;
            }
        }
    }

    // ---- prologue: load B-frags of tile 'off' + its e2 ----
    // packet layout per tile (384 packets): spl0Ks0 @0, spl0Ks1 @64,
    // spl1Ks0 @128, spl1Ks1 @192, spl2Ks0 @256, spl2Ks1 @320 (+lane).
    const bf16x8* ep0 = epack + (size_t)(tile0 + off) * 384;
    bf16x8 Bh0 = ep0[lane];
    bf16x8 Bh1 = ep0[64  + lane];
    bf16x8 Bm0 = ep0[128 + lane];
    bf16x8 Bm1 = ep0[192 + lane];
    bf16x8 Bl0 = ep0[256 + lane];
    bf16x8 Bl1 = ep0[320 + lane];
    float e2v  = e2g[off * 16 + l15];

    float bestd[8] = {INFINITY, INFINITY, INFINITY, INFINITY,
                      INFINITY, INFINITY, INFINITY, INFINITY};
    int   bt[8]    = {0, 0, 0, 0, 0, 0, 0, 0};

    for (int tt = 0; tt < TPC; ++tt) {
        const int t  = (tt + off) & (TPC - 1);        // actual tile index
        const int tn = (tt + 1 + off) & (TPC - 1);    // next (wrap: harmless)

        // ---- compute on current B regs ----
        f32x4 acc0 = {0.f, 0.f, 0.f, 0.f};
        f32x4 acc1 = {0.f, 0.f, 0.f, 0.f};
        __builtin_amdgcn_s_setprio(1);
        // combos: hh, mh, lh, hm, mm, hl  (x 2 row-tiles), Ks=0 then Ks=1
        acc0 = __builtin_amdgcn_mfma_f32_16x16x32_bf16(A[0][0][0], Bh0, acc0, 0, 0, 0);
        acc1 = __builtin_amdgcn_mfma_f32_16x16x32_bf16(A[1][0][0], Bh0, acc1, 0, 0, 0);
        acc0 = __builtin_amdgcn_mfma_f32_16x16x32_bf16(A[0][0][1], Bh0, acc0, 0, 0, 0);
        acc1 = __builtin_amdgcn_mfma_f32_16x16x32_bf16(A[1][0][1], Bh0, acc1, 0, 0, 0);
        acc0 = __builtin_amdgcn_mfma_f32_16x16x32_bf16(A[0][0][2], Bh0, acc0, 0, 0, 0);
        acc1 = __builtin_amdgcn_mfma_f32_16x16x32_bf16(A[1][0][2], Bh0, acc1, 0, 0, 0);
        acc0 = __builtin_amdgcn_mfma_f32_16x16x32_bf16(A[0][0][1], Bm0, acc0, 0, 0, 0);
        acc1 = __builtin_amdgcn_mfma_f32_16x16x32_bf16(A[1][0][1], Bm0, acc1, 0, 0, 0);
        acc0 = __builtin_amdgcn_mfma_f32_16x16x32_bf16(A[0][0][0], Bm0, acc0, 0, 0, 0);
        acc1 = __builtin_amdgcn_mfma_f32_16x16x32_bf16(A[1][0][0], Bm0, acc1, 0, 0, 0);
        acc0 = __builtin_amdgcn_mfma_f32_16x16x32_bf16(A[0][0][0], Bl0, acc0, 0, 0, 0);
        acc1 = __builtin_amdgcn_mfma_f32_16x16x32_bf16(A[1][0][0], Bl0, acc1, 0, 0, 0);
        acc0 = __builtin_amdgcn_mfma_f32_16x16x32_bf16(A[0][1][0], Bh1, acc0, 0, 0, 0);
        acc1 = __builtin_amdgcn_mfma_f32_16x16x32_bf16(A[1][1][0], Bh1, acc1, 0, 0, 0);
        acc0 = __builtin_amdgcn_mfma_f32_16x16x32_bf16(A[0][1][1], Bh1, acc0, 0, 0, 0);
        acc1 = __builtin_amdgcn_mfma_f32_16x16x32_bf16(A[1][1][1], Bh1, acc1, 0, 0, 0);
        acc0 = __builtin_amdgcn_mfma_f32_16x16x32_bf16(A[0][1][2], Bh1, acc0, 0, 0, 0);
        acc1 = __builtin_amdgcn_mfma_f32_16x16x32_bf16(A[1][1][2], Bh1, acc1, 0, 0, 0);
        acc0 = __builtin_amdgcn_mfma_f32_16x16x32_bf16(A[0][1][1], Bm1, acc0, 0, 0, 0);
        acc1 = __builtin_amdgcn_mfma_f32_16x16x32_bf16(A[1][1][1], Bm1, acc1, 0, 0, 0);
        acc0 = __builtin_amdgcn_mfma_f32_16x16x32_bf16(A[0][1][0], Bm1, acc0, 0, 0, 0);
        acc1 = __builtin_amdgcn_mfma_f32_16x16x32_bf16(A[1][1][0], Bm1, acc1, 0, 0, 0);
        acc0 = __builtin_amdgcn_mfma_f32_16x16x32_bf16(A[0][1][0], Bl1, acc0, 0, 0, 0);
        acc1 = __builtin_amdgcn_mfma_f32_16x16x32_bf16(A[1][1][0], Bl1, acc1, 0, 0, 0);
        __builtin_amdgcn_s_setprio(0);

        // ---- B regs are dead now: issue next tile's loads into them ----
        const bf16x8* epn = epack + (size_t)(tile0 + tn) * 384;
        Bh0 = epn[lane];
        Bh1 = epn[64  + lane];
        Bm0 = epn[128 + lane];
        Bm1 = epn[192 + lane];
        Bl0 = epn[256 + lane];
        Bl1 = epn[320 + lane];
        const float e2cur = e2v;
        e2v = e2g[tn * 16 + l15];

        // ---- fold: score = e2 - 2*dot (z2 row-constant, dropped) ----
#pragma unroll
        for (int v = 0; v < 4; ++v) {
            float d0 = fmaf(-2.0f, acc0[v], e2cur);
            if (d0 < bestd[v])     { bestd[v]     = d0; bt[v]     = t; }
            float d1 = fmaf(-2.0f, acc1[v], e2cur);
            if (d1 < bestd[4 + v]) { bestd[4 + v] = d1; bt[4 + v] = t; }
        }
    }

    // ---- cross-lane min over the 16 cw-lanes, then atomicMin merge ----
    // (u64 pack: min dist, tie -> min cw == first occurrence; visit-order
    //  independent, so the tile-offset stagger is safe.)
#pragma unroll
    for (int mt = 0; mt < 2; ++mt) {
#pragma unroll
        for (int v = 0; v < 4; ++v) {
            float bd = bestd[mt * 4 + v];
            int   cw = chunkbase + bt[mt * 4 + v] * 16 + l15;
            unsigned db = __float_as_uint(bd);
            db = (db & 0x80000000u) ? ~db : (db | 0x80000000u);
            unsigned long long key =
                ((unsigned long long)db << 32) | (unsigned)cw;
#pragma unroll
            for (int off2 = 1; off2 < 16; off2 <<= 1) {
                unsigned long long o = __shfl_xor(key, off2);
                key = (o < key) ? o : key;
            }
            if (l15 == 0)
                atomicMin(&best[rowbase + mt * 16 + l4 * 4 + v], key);
        }
    }
}

// ---------------- kernel 3: gather + straight-through output + loss ---
__global__ __launch_bounds__(256) void vq_out_kernel(
    const float* __restrict__ z, const float* __restrict__ emb,
    const unsigned long long* __restrict__ best,
    float* __restrict__ out, float* __restrict__ lsum) {
    const int base = (blockIdx.x * 256 + threadIdx.x) * 8;
    const int row  = base >> 6;
    const int m    = (int)(best[row] & 0xFFFFFFFFull);

    const float4* zp = reinterpret_cast<const float4*>(z + base);
    const float4* qp = reinterpret_cast<const float4*>(emb + (size_t)m * WORD + (base & 63));
    float4* op = reinterpret_cast<float4*>(out + base);

    float s = 0.f;
#pragma unroll
    for (int i = 0; i < 2; ++i) {
        float4 zv = zp[i];
        float4 qv = qp[i];
        float dx = qv.x - zv.x, dy = qv.y - zv.y, dz = qv.z - zv.z, dw = qv.w - zv.w;
        float4 ov;
        ov.x = zv.x + dx; ov.y = zv.y + dy; ov.z = zv.z + dz; ov.w = zv.w + dw;
        op[i] = ov;
        s += dx*dx + dy*dy + dz*dz + dw*dw;
    }

#pragma unroll
    for (int off = 32; off > 0; off >>= 1) s += __shfl_down(s, off);
    __shared__ float wsum[4];
    int lane = threadIdx.x & 63, wid = threadIdx.x >> 6;
    if (lane == 0) wsum[wid] = s;
    __syncthreads();
    if (threadIdx.x == 0)
        atomicAdd(lsum, (wsum[0] + wsum[1]) + (wsum[2] + wsum[3]));
}

// ---------------- kernel 4: finalize loss -----------------------------
__global__ void vq_loss_kernel(const float* __restrict__ lsum,
                               float* __restrict__ loss_out) {
    float mean = lsum[0] * (1.0f / (float)NELEM);
    loss_out[0] = mean + 2.5f * mean;
}

extern "C" void kernel_launch(void* const* d_in, const int* in_sizes, int n_in,
                              void* d_out, int out_size, void* d_ws, size_t ws_size,
                              hipStream_t stream) {
    const float* z   = (const float*)d_in[0];   // z_mean (2048,1024)
    // d_in[1] = z_log_var, unused by the reference
    const float* emb = (const float*)d_in[2];   // (8192,64)
    float* out = (float*)d_out;                 // [z_q_st flat (2097152), loss]

    // ws layout: epack 3 MB | e2 32 KB | best 256 KB | lsum 4 B
    bf16x8* epack = (bf16x8*)d_ws;
    float*  e2    = (float*)((char*)d_ws + (size_t)PKTS * 16);
    unsigned long long* best =
        (unsigned long long*)((char*)e2 + NB_WORD * sizeof(float));
    float* lsum = (float*)((char*)best + NROWS * sizeof(unsigned long long));

    hipMemsetAsync(best, 0xFF, NROWS * sizeof(unsigned long long), stream);
    hipMemsetAsync(lsum, 0, sizeof(float), stream);

    vq_prep_kernel<<<NB_WORD / 256, 256, 0, stream>>>(emb, e2, epack);
    vq_argmin_kernel<<<dim3(NROWS / 128, NCHUNK), 256, 0, stream>>>(
        z, epack, e2, best);
    vq_out_kernel<<<NELEM / (256 * 8), 256, 0, stream>>>(z, emb, best, out, lsum);
    vq_loss_kernel<<<1, 1, 0, stream>>>(lsum, out + NELEM);
}